// Round 2
// baseline (222.630 us; speedup 1.0000x reference)
//
#include <hip/hip_runtime.h>

// Levenshtein edit distance, ref (512,B) x hyp (512,B), B=1024, unit costs.
// Anti-diagonal wavefront, one 64-lane wave per batch element, 8 cells/lane.
//
// Domain: w = (v - d) + 1024  (biased relative values, w in [0,1024] for real
// cells; fake "infinity" = 2047 fits 12 bits and decreases <=2/step so it
// stays > 1024 until the real frontier arrives).
// Recurrence: AN[k] = min3(A1[k-1], A1[k], A2[k-1] - 1 - eq).
// Boundary (i=0): w = 1024 exactly (row D[0][j] = j). Final answer: w = v.
//
// Cross-lane traffic reduced to ONE packed shuffle per step:
//   pack = (ht[6] << 12) | AN[7]   (token 10 bits | value 12 bits)
// issued right after AN[7] (the 1-op critical chain), consumed one full step
// later at the receiving lane's k=0 cell -> DS latency hidden behind a step
// of VALU work. shfl(A2[7]) is algebraically last step's shfl(A1[7]) -> carry
// its low 12 bits in `prevlow` instead of shuffling again.

#define RLEN 512
#define HLEN 512
#define BATCH 1024
#define BIAS 1024
#define FAKE 2047   // fake infinity, fits 12 bits, > any real biased value
#define SENT 1023   // token sentinel; real tokens < 1000

// A2 = diag d-2, A1 = diag d-1, AN = output diag d (all biased).
#define STEP(A2, A1, AN, tok_inject)                                   \
  {                                                                    \
    /* top cell first: 1-op chain, feeds next step's shuffle */        \
    int c7 = A2[6] - 1 - (rt[7] == ht[7]);                             \
    AN[7] = min(min(A1[6], A1[7]), c7);                                \
    int nxt = __shfl_up((ht[6] << 12) | AN[7], 1);                     \
    _Pragma("unroll")                                                  \
    for (int k = 6; k >= 1; --k) {                                     \
      int ck = A2[k - 1] - 1 - (rt[k] == ht[k]);                       \
      AN[k] = min(min(A1[k - 1], A1[k]), ck);                          \
    }                                                                  \
    /* k=0 consumes the shuffle issued LAST step (cur) */              \
    int a1m = (lane == 0) ? BIAS : (cur & 0xFFF);                      \
    int a2m = (lane == 0) ? BIAS : prevlow;                            \
    int c0 = a2m - 1 - (rt[0] == ht[0]);                               \
    AN[0] = min(min(a1m, A1[0]), c0);                                  \
    /* shift token queue; inject at lane 0, else from last shuffle */  \
    _Pragma("unroll")                                                  \
    for (int k = 7; k >= 1; --k) ht[k] = ht[k - 1];                    \
    ht[0] = (lane == 0) ? (tok_inject) : (cur >> 12);                  \
    prevlow = cur & 0xFFF;                                             \
    cur = nxt;                                                         \
  }

__global__ __launch_bounds__(64, 1)
void edit_distance_kernel(const int* __restrict__ ref,
                          const int* __restrict__ hyp,
                          float* __restrict__ out) {
  const int b = blockIdx.x;        // one wave per batch element
  const int lane = threadIdx.x;    // 0..63

  // Static ref tokens: cell c = lane*8+k  (matrix row i = c+1).
  int rt[8];
#pragma unroll
  for (int k = 0; k < 8; ++k)
    rt[k] = ref[(lane * 8 + k) * BATCH + b];

  // Rotating diagonal buffers (biased domain).
  int A[8], Bv[8], Cv[8];
#pragma unroll
  for (int k = 0; k < 8; ++k) { A[k] = FAKE; Bv[k] = FAKE; }
  if (lane == 0) Bv[0] = BIAS;  // D[1][0]=1 on diag d=1 -> w = 1024

  // Hyp token queue: ht[k] at step d holds hyp0[d-c-2] for cell c.
  int ht[8];
#pragma unroll
  for (int k = 0; k < 8; ++k) ht[k] = SENT;
  if (lane == 0) ht[0] = hyp[b];  // consumed by cell 0 at d=2

  // Pipeline state for the packed shuffle.
  int cur = __shfl_up((SENT << 12) | Bv[7], 1);  // consumed at step d=2
  int prevlow = FAKE;                            // (lane-1) A2[7] at d=2

  // Scalar-prefetched injection tokens: step d injects hyp0[d-1] (clamped).
  int d = 2;
  int t0 = hyp[min(d - 1, HLEN - 1) * BATCH + b];
  int t1 = hyp[min(d + 0, HLEN - 1) * BATCH + b];
  int t2 = hyp[min(d + 1, HLEN - 1) * BATCH + b];

  // 1023 diagonal steps (d = 2..1024), 3 per iteration, 341 iterations.
  for (int it = 0; it < 341; ++it) {
    int n0 = hyp[min(d + 2, HLEN - 1) * BATCH + b];
    int n1 = hyp[min(d + 3, HLEN - 1) * BATCH + b];
    int n2 = hyp[min(d + 4, HLEN - 1) * BATCH + b];
    STEP(A, Bv, Cv, t0);   // diag d
    STEP(Bv, Cv, A, t1);   // diag d+1
    STEP(Cv, A, Bv, t2);   // diag d+2
    d += 3;
    t0 = n0; t1 = n1; t2 = n2;
  }

  // Answer: D[512][512] on diag 1024 lives in Bv, cell 511 = lane 63, k=7.
  // Biased domain at d = 1024 = BIAS gives w = v exactly.
  if (lane == 63) out[b] = (float)Bv[7];
}

extern "C" void kernel_launch(void* const* d_in, const int* in_sizes, int n_in,
                              void* d_out, int out_size, void* d_ws, size_t ws_size,
                              hipStream_t stream) {
  const int* ref = (const int*)d_in[0];
  const int* hyp = (const int*)d_in[1];
  float* out = (float*)d_out;
  edit_distance_kernel<<<BATCH, 64, 0, stream>>>(ref, hyp, out);
}

// Round 3
// 193.617 us; speedup vs baseline: 1.1499x; 1.1499x over previous
//
#include <hip/hip_runtime.h>

// Levenshtein edit distance, ref (512,B) x hyp (512,B), B=1024, unit costs.
// Anti-diagonal wavefront, one 64-lane wave per batch element, 8 cells/lane.
// Values stored relative to the diagonal index d (v' = v - d):
//   new'[i] = min(D1'[i-1], D1'[i], D2'[i-1] + (ref_i==hyp_{d-i} ? -2 : -1))
// i=0 boundary injects constant 0; j=0 boundary emerges from LARGE init.
//
// Cross-lane: DS-path __shfl_up (ds_bpermute, ~120+ cyc, unhidable at 1
// wave/SIMD) replaced by DPP WAVE_SHR1 (0x138) v_mov_b32_dpp — a ~2-4 cyc
// VALU op. bound_ctrl=0 makes lane 0 receive `old`, folding the boundary
// injection into the same instruction.

#define RLEN 512
#define HLEN 512
#define BATCH 1024
#define LARGE (1 << 20)

// lane L gets src from lane L-1; lane 0 gets `old`. (gfx9 DPP WAVE_SHR1)
__device__ __forceinline__ int shfl_up1(int old, int src) {
  return __builtin_amdgcn_update_dpp(old, src, 0x138, 0xF, 0xF, false);
}

// A2 = diag d-2 (rel d-2), A1 = diag d-1 (rel d-1), AN = output diag d.
// Also shifts the hyp-token queue, injecting tok_inject at lane 0 cell 0.
#define STEP(A2, A1, AN, tok_inject)                                  \
  {                                                                   \
    int a1m = shfl_up1(0, A1[7]);        /* D1'[i-1] for k==0 */      \
    int a2m = shfl_up1(0, A2[7]);        /* D2'[i-1] for k==0 */      \
    int uph = shfl_up1(tok_inject, ht[7]);                            \
    _Pragma("unroll")                                                 \
    for (int k = 7; k >= 1; --k) {                                    \
      int cand = A2[k - 1] - 1 - (rt[k] == ht[k]);                    \
      AN[k] = min(min(A1[k - 1], A1[k]), cand);                       \
    }                                                                 \
    int c0 = a2m - 1 - (rt[0] == ht[0]);                              \
    AN[0] = min(min(a1m, A1[0]), c0);                                 \
    _Pragma("unroll")                                                 \
    for (int k = 7; k >= 1; --k) ht[k] = ht[k - 1];                   \
    ht[0] = uph;                                                      \
  }

__global__ __launch_bounds__(64, 1)
void edit_distance_kernel(const int* __restrict__ ref,
                          const int* __restrict__ hyp,
                          float* __restrict__ out) {
  const int b = blockIdx.x;        // one wave (block of 64) per batch element
  const int lane = threadIdx.x;    // 0..63

  // Static ref tokens for this wave's cells c = lane*8+k  (i = c+1).
  int rt[8];
#pragma unroll
  for (int k = 0; k < 8; ++k)
    rt[k] = ref[(lane * 8 + k) * BATCH + b];

  // Three rotating diagonal buffers (relative domain).
  int A[8], Bv[8], Cv[8];
#pragma unroll
  for (int k = 0; k < 8; ++k) { A[k] = LARGE; Bv[k] = LARGE; }
  if (lane == 0) Bv[0] = 0;  // D[1][0]=1, rel diag d=1 -> 0

  // Hyp token queue: ht[k] = token for cell c at current step d = hyp0[d-c-2].
  int ht[8];
#pragma unroll
  for (int k = 0; k < 8; ++k) ht[k] = -1;
  if (lane == 0) ht[0] = hyp[b];  // hyp0[0], consumed by cell 0 at d=2

  // Scalar-prefetched injection tokens: step d injects hyp0[d-1] (clamped).
  int d = 2;
  int t0 = hyp[min(d - 1, HLEN - 1) * BATCH + b];
  int t1 = hyp[min(d + 0, HLEN - 1) * BATCH + b];
  int t2 = hyp[min(d + 1, HLEN - 1) * BATCH + b];

  // 1023 diagonal steps (d = 2..1024), 3 per iteration, 341 iterations.
  for (int it = 0; it < 341; ++it) {
    int n0 = hyp[min(d + 2, HLEN - 1) * BATCH + b];
    int n1 = hyp[min(d + 3, HLEN - 1) * BATCH + b];
    int n2 = hyp[min(d + 4, HLEN - 1) * BATCH + b];
    STEP(A, Bv, Cv, t0);   // diag d
    STEP(Bv, Cv, A, t1);   // diag d+1
    STEP(Cv, A, Bv, t2);   // diag d+2
    d += 3;
    t0 = n0; t1 = n1; t2 = n2;
  }

  // Answer: D[512][512] on diag 1024 = Bv (last write), cell 511 = lane 63 k=7.
  if (lane == 63) out[b] = (float)(Bv[7] + (RLEN + HLEN));
}

extern "C" void kernel_launch(void* const* d_in, const int* in_sizes, int n_in,
                              void* d_out, int out_size, void* d_ws, size_t ws_size,
                              hipStream_t stream) {
  const int* ref = (const int*)d_in[0];
  const int* hyp = (const int*)d_in[1];
  float* out = (float*)d_out;
  edit_distance_kernel<<<BATCH, 64, 0, stream>>>(ref, hyp, out);
}

// Round 4
// 184.868 us; speedup vs baseline: 1.2043x; 1.0473x over previous
//
#include <hip/hip_runtime.h>

// Levenshtein edit distance, ref (512,B) x hyp (512,B), B=1024, unit costs.
// Anti-diagonal wavefront, one 64-lane wave per batch element, 8 cells/lane.
// Values relative to diagonal index d (v' = v - d):
//   new'[i] = min(A1'[i-1], A1'[i], A2'[i-1] + nq - 2),  nq = (ref_i!=hyp) ? 1 : 0
// i=0 boundary injects constant 0 (DPP old-operand); j=0 boundary emerges
// from LARGE init (verified absmax=0 since round 1).
//
// Round-4 changes (theory: serial schedule at ~4.7 cyc/instr under a
// 24-VGPR allocation; 8 independent cells/step give ILP 8 if RA allows):
//  - amdgpu_waves_per_eu(1): optimize for 1 wave/EU, lift register pressure
//    minimization so the scheduler interleaves cells.
//  - vcc-free equality: nq = min(|rt-ht|,1) -> v_sub/v_max/v_min/v_add3,
//    no v_cmp/v_cndmask serialization through the single vcc register.

#define RLEN 512
#define HLEN 512
#define BATCH 1024
#define LARGE (1 << 20)

// lane L gets src from lane L-1; lane 0 gets `old` (gfx9 DPP WAVE_SHR1,
// bound_ctrl=false keeps old in invalid lanes). HW-verified in round 3.
__device__ __forceinline__ int shfl_up1(int old, int src) {
  return __builtin_amdgcn_update_dpp(old, src, 0x138, 0xF, 0xF, false);
}

// A2 = diag d-2 (rel), A1 = diag d-1 (rel), AN = output diag d (rel).
// Also shifts the hyp-token queue, injecting tok_inject at lane 0 cell 0.
#define STEP(A2, A1, AN, tok_inject)                                  \
  {                                                                   \
    int a1m = shfl_up1(0, A1[7]);        /* A1'[i-1] for k==0 */      \
    int a2m = shfl_up1(0, A2[7]);        /* A2'[i-1] for k==0 */      \
    int uph = shfl_up1(tok_inject, ht[7]);                            \
    _Pragma("unroll")                                                 \
    for (int k = 7; k >= 1; --k) {                                    \
      int df = rt[k] - ht[k];                                         \
      int ab = max(df, -df);                                          \
      int nq = min(ab, 1);                                            \
      AN[k] = min(min(A1[k - 1], A1[k]), A2[k - 1] + nq - 2);         \
    }                                                                 \
    {                                                                 \
      int df = rt[0] - ht[0];                                         \
      int ab = max(df, -df);                                          \
      int nq = min(ab, 1);                                            \
      AN[0] = min(min(a1m, A1[0]), a2m + nq - 2);                     \
    }                                                                 \
    _Pragma("unroll")                                                 \
    for (int k = 7; k >= 1; --k) ht[k] = ht[k - 1];                   \
    ht[0] = uph;                                                      \
  }

__global__ void __launch_bounds__(64)
__attribute__((amdgpu_waves_per_eu(1)))
edit_distance_kernel(const int* __restrict__ ref,
                     const int* __restrict__ hyp,
                     float* __restrict__ out) {
  const int b = blockIdx.x;        // one wave (block of 64) per batch element
  const int lane = threadIdx.x;    // 0..63

  // Static ref tokens for this wave's cells c = lane*8+k  (i = c+1).
  int rt[8];
#pragma unroll
  for (int k = 0; k < 8; ++k)
    rt[k] = ref[(lane * 8 + k) * BATCH + b];

  // Three rotating diagonal buffers (relative domain).
  int A[8], Bv[8], Cv[8];
#pragma unroll
  for (int k = 0; k < 8; ++k) { A[k] = LARGE; Bv[k] = LARGE; }
  if (lane == 0) Bv[0] = 0;  // D[1][0]=1, rel diag d=1 -> 0

  // Hyp token queue: ht[k] = token for cell c at current step d = hyp0[d-c-2].
  int ht[8];
#pragma unroll
  for (int k = 0; k < 8; ++k) ht[k] = -1;
  if (lane == 0) ht[0] = hyp[b];  // hyp0[0], consumed by cell 0 at d=2

  // Scalar-prefetched injection tokens: step d injects hyp0[d-1] (clamped).
  int d = 2;
  int t0 = hyp[min(d - 1, HLEN - 1) * BATCH + b];
  int t1 = hyp[min(d + 0, HLEN - 1) * BATCH + b];
  int t2 = hyp[min(d + 1, HLEN - 1) * BATCH + b];

  // 1023 diagonal steps (d = 2..1024), 3 per iteration, 341 iterations.
  for (int it = 0; it < 341; ++it) {
    int n0 = hyp[min(d + 2, HLEN - 1) * BATCH + b];
    int n1 = hyp[min(d + 3, HLEN - 1) * BATCH + b];
    int n2 = hyp[min(d + 4, HLEN - 1) * BATCH + b];
    STEP(A, Bv, Cv, t0);   // diag d
    STEP(Bv, Cv, A, t1);   // diag d+1
    STEP(Cv, A, Bv, t2);   // diag d+2
    d += 3;
    t0 = n0; t1 = n1; t2 = n2;
  }

  // Answer: D[512][512] on diag 1024 = Bv (last write), cell 511 = lane 63 k=7.
  if (lane == 63) out[b] = (float)(Bv[7] + (RLEN + HLEN));
}

extern "C" void kernel_launch(void* const* d_in, const int* in_sizes, int n_in,
                              void* d_out, int out_size, void* d_ws, size_t ws_size,
                              hipStream_t stream) {
  const int* ref = (const int*)d_in[0];
  const int* hyp = (const int*)d_in[1];
  float* out = (float*)d_out;
  edit_distance_kernel<<<BATCH, 64, 0, stream>>>(ref, hyp, out);
}